// Round 7
// baseline (223.319 us; speedup 1.0000x reference)
//
#include <hip/hip_runtime.h>
#include <hip/hip_bf16.h>

typedef unsigned short u16;
typedef unsigned int   u32;

using bf8 = __attribute__((ext_vector_type(8))) __bf16;
using f4  = __attribute__((ext_vector_type(4))) float;

__device__ __forceinline__ float b2f(u16 u) {
    union { u32 i; float f; } v; v.i = ((u32)u) << 16; return v.f;
}
__device__ __forceinline__ u16 f2b(float f) {
    union { float f; u32 i; } v; v.f = f;
    u32 x = v.i;
    x += 0x7fffu + ((x >> 16) & 1u);   // RNE
    return (u16)(x >> 16);
}
// Packed fp32x2 -> bf16x2 (low = first arg). HW v_cvt_pk_bf16_f32 on gfx950.
__device__ __forceinline__ u32 pk2(float lo, float hi) {
    union { __hip_bfloat162 h; u32 u; } v;
    v.h = __float22bfloat162_rn(make_float2(lo, hi));
    return v.u;
}

// ---------------------------------------------------------------------------
// Weight swizzle v2: 36 blocks x 256 thr. Each block = one 32-row k-slab of
// one matrix. Coalesced float4 row reads -> bf16 LDS slab (stride 270 breaks
// bank alignment) -> per-lane fragment assembly -> coalesced dwordx4 stores.
// Output layout identical to verified v1:
// dst[((kt*16+ct)*64+lane)*8+j] = bf16(W[kt*32+(lane>>4)*8+j][ct*16+(lane&15)])
// ---------------------------------------------------------------------------
__global__ void swz_all(const float* __restrict__ w1, const float* __restrict__ w3,
                        const float* __restrict__ w2, const float* __restrict__ w4,
                        const float* __restrict__ w5, const float* __restrict__ w7,
                        u16* __restrict__ ws) {
    __shared__ u16 slab[32 * 270];
    int b = blockIdx.x, t = threadIdx.x;
    const float* src; u16* dst; int kmax, kt;
    if      (b <  2) { src = w1; dst = ws;          kmax = 54;  kt = b;      }
    else if (b <  4) { src = w3; dst = ws + 16384;  kmax = 54;  kt = b - 2;  }
    else if (b < 12) { src = w2; dst = ws + 32768;  kmax = 256; kt = b - 4;  }
    else if (b < 20) { src = w4; dst = ws + 98304;  kmax = 256; kt = b - 12; }
    else if (b < 28) { src = w5; dst = ws + 163840; kmax = 256; kt = b - 20; }
    else             { src = w7; dst = ws + 229376; kmax = 256; kt = b - 28; }

    #pragma unroll
    for (int it = 0; it < 8; ++it) {
        int flat = it * 1024 + t * 4;           // 0..8188, 4 elems/thread
        int row = flat >> 8, col = flat & 255;
        int k = kt * 32 + row;
        float4 v = make_float4(0.f, 0.f, 0.f, 0.f);
        if (k < kmax) v = *(const float4*)(src + k * 256 + col);
        u32* sp = (u32*)&slab[row * 270 + col];  // col%4==0, 270 even -> 4B ok
        sp[0] = pk2(v.x, v.y);
        sp[1] = pk2(v.z, v.w);
    }
    __syncthreads();

    int lane = t & 63, wave = t >> 6, lr = lane & 15, kg = lane >> 4;
    #pragma unroll
    for (int i = 0; i < 4; ++i) {
        int ct = wave * 4 + i;
        u16 v[8];
        #pragma unroll
        for (int j = 0; j < 8; ++j)
            v[j] = slab[(kg * 8 + j) * 270 + ct * 16 + lr];
        uint4 o;
        o.x = (u32)v[0] | ((u32)v[1] << 16);
        o.y = (u32)v[2] | ((u32)v[3] << 16);
        o.z = (u32)v[4] | ((u32)v[5] << 16);
        o.w = (u32)v[6] | ((u32)v[7] << 16);
        *(uint4*)(dst + (size_t)(((kt * 16 + ct) * 64 + lane) * 8)) = o;
    }
}

// ---------------------------------------------------------------------------
// Fused critic. One WG = 32 batch rows. LDS pool (u16 elems):
//   inp  [0, 6912)        96 rows x 72  (L1 A-operand)
//   h    [6912, 32256)    96 rows x 264 (x1 / S1+S2 / rho-h, region reused)
// staging (gather) transiently at [6912, 10112); dot partials at [0,512) u32.
// MFMA mappings verified end-to-end in rounds 2/3/6.
// ---------------------------------------------------------------------------
#define H_OFF 6912
#define RH0   (H_OFF + 16896)   // rho-h net0: h rows 64..95
#define RH1   (H_OFF + 16)      // rho-h net1: over consumed S1 (+16 elem shift)

__global__ __launch_bounds__(256, 2) void critic_kernel(
    const float* __restrict__ obs, const float* __restrict__ ag,
    const float* __restrict__ g,   const float* __restrict__ anchor,
    const float* __restrict__ act,
    const float* __restrict__ b1,  const float* __restrict__ b2,
    const float* __restrict__ b3,  const float* __restrict__ b4,
    const float* __restrict__ b5,  const float* __restrict__ b7,
    const float* __restrict__ w6,  const float* __restrict__ b6,
    const float* __restrict__ w8,  const float* __restrict__ b8,
    const u16* __restrict__ wsz, float* __restrict__ out, int B) {

    __shared__ u16 pool[32256];

    const int t    = threadIdx.x;
    const int lane = t & 63;
    const int wave = t >> 6;
    const int lr   = lane & 15;
    const int lg   = lane >> 4;
    const int wg   = blockIdx.x;

    // ---- Stage raw activations into LDS (coalesced) ----
    const int STG = H_OFF;           // transient, dead before L1 epilogue
    for (int i = t; i < 1760; i += 256) {             // obs 32x55 -> stride 56
        int b = i / 55, c = i - b * 55;
        pool[STG + b * 56 + c] = f2b(obs[wg * 1760 + i]);
    }
    for (int i = t; i < 288; i += 256) {              // ag 32x9 -> stride 10
        int b = i / 9, c = i - b * 9;
        pool[STG + 1792 + b * 10 + c] = f2b(ag[wg * 288 + i]);
    }
    for (int i = t; i < 288; i += 256) {              // g
        int b = i / 9, c = i - b * 9;
        pool[STG + 2112 + b * 10 + c] = f2b(g[wg * 288 + i]);
    }
    if (t < 128)                                      // act 32x4
        pool[STG + 2432 + t] = f2b(act[wg * 128 + t]);
    for (int i = t; i < 288; i += 256) {              // anchor kept fp32!
        int b = i / 9, c = i - b * 9;
        ((u32*)pool)[(STG + 2560) / 2 + b * 10 + c] = __float_as_uint(anchor[wg * 288 + i]);
    }
    __syncthreads();

    // ---- Build pair inputs (96 rows x 54, zero-pad to 64) from LDS ----
    if (t < 96) {
        const int O1[3] = {0, 0, 1}, O2[3] = {1, 2, 2};
        const int JA[3] = {3, 4, 6}, KA[3] = {5, 7, 8};
        int p = t / 32, bl = t % 32;
        int j = JA[p], k = KA[p];
        float aj = __uint_as_float(((u32*)pool)[(STG + 2560) / 2 + bl * 10 + j]);
        float ak = __uint_as_float(((u32*)pool)[(STG + 2560) / 2 + bl * 10 + k]);
        bool sel = (aj - ak) >= 0.0f;
        int bit2 = sel ? j : k;
        int oi = sel ? O1[p] : O2[p];
        int oj = sel ? O2[p] : O1[p];
        u16* row = &pool[t * 72];
        row[0] = pool[STG + 1792 + bl * 10 + p];
        row[1] = pool[STG + 1792 + bl * 10 + bit2];
        row[2] = pool[STG + 2112 + bl * 10 + p];
        row[3] = pool[STG + 2112 + bl * 10 + bit2];
        for (int c = 0; c < 10; ++c) row[4 + c] = pool[STG + bl * 56 + c];
        const u16 ONE = 0x3F80;
        row[14] = (oi == 0) ? ONE : 0; row[15] = (oi == 1) ? ONE : 0; row[16] = (oi == 2) ? ONE : 0;
        for (int c = 0; c < 15; ++c) row[17 + c] = pool[STG + bl * 56 + 10 + 15 * oi + c];
        row[32] = (oj == 0) ? ONE : 0; row[33] = (oj == 1) ? ONE : 0; row[34] = (oj == 2) ? ONE : 0;
        for (int c = 0; c < 15; ++c) row[35 + c] = pool[STG + bl * 56 + 10 + 15 * oj + c];
        for (int c = 0; c < 4; ++c)  row[50 + c] = pool[STG + 2432 + bl * 4 + c];
        for (int c = 54; c < 64; ++c) row[c] = 0;
    }
    __syncthreads();

    f4  sacc[2][4];      // net1 (S2) pair-sums, fp32
    u32 s1p[2][4][2];    // net0 (S1) pair-sums, packed bf16

    // ---- Phi networks (net 0: w1/w2, net 1: w3/w4) ----
    for (int net = 0; net < 2; ++net) {
        const u16* Wl1 = wsz + (net ? 16384 : 0);
        const u16* Wl2 = wsz + 32768 + (net ? 65536 : 0);
        const float* bl1 = net ? b3 : b1;
        const float* bl2 = net ? b4 : b2;

        // Layer 1: (96 x 64) @ (64 x 256)
        f4 acc[6][4];
        #pragma unroll
        for (int rt = 0; rt < 6; ++rt)
            #pragma unroll
            for (int c = 0; c < 4; ++c) acc[rt][c] = (f4){0.f, 0.f, 0.f, 0.f};
        #pragma unroll
        for (int kt = 0; kt < 2; ++kt) {
            bf8 bfr[4];
            #pragma unroll
            for (int c = 0; c < 4; ++c)
                bfr[c] = *(const bf8*)(Wl1 + (size_t)(((kt * 16 + wave * 4 + c) * 64 + lane) * 8));
            #pragma unroll
            for (int rt = 0; rt < 6; ++rt) {
                bf8 afr = *(const bf8*)(&pool[(rt * 16 + lr) * 72 + kt * 32 + lg * 8]);
                #pragma unroll
                for (int c = 0; c < 4; ++c)
                    acc[rt][c] = __builtin_amdgcn_mfma_f32_16x16x32_bf16(afr, bfr[c], acc[rt][c], 0, 0, 0);
            }
        }
        #pragma unroll
        for (int c = 0; c < 4; ++c) {
            float bias = bl1[(wave * 4 + c) * 16 + lr];
            #pragma unroll
            for (int rt = 0; rt < 6; ++rt) {
                u32 p01 = pk2(fmaxf(acc[rt][c][0] + bias, 0.f), fmaxf(acc[rt][c][1] + bias, 0.f));
                u32 p23 = pk2(fmaxf(acc[rt][c][2] + bias, 0.f), fmaxf(acc[rt][c][3] + bias, 0.f));
                int base = H_OFF + (rt * 16 + lg * 4) * 264 + (wave * 4 + c) * 16 + lr;
                pool[base]           = (u16)p01;
                pool[base + 264]     = (u16)(p01 >> 16);
                pool[base + 2 * 264] = (u16)p23;
                pool[base + 3 * 264] = (u16)(p23 >> 16);
            }
        }
        __syncthreads();

        // Layer 2: (96 x 256) @ (256 x 256), relu, pair-sum
        f4 acc2[6][4];
        #pragma unroll
        for (int rt = 0; rt < 6; ++rt)
            #pragma unroll
            for (int c = 0; c < 4; ++c) acc2[rt][c] = (f4){0.f, 0.f, 0.f, 0.f};
        #pragma unroll
        for (int ks = 0; ks < 8; ++ks) {
            bf8 bfr[4];
            #pragma unroll
            for (int c = 0; c < 4; ++c)
                bfr[c] = *(const bf8*)(Wl2 + (size_t)(((ks * 16 + wave * 4 + c) * 64 + lane) * 8));
            #pragma unroll
            for (int rt = 0; rt < 6; ++rt) {
                bf8 afr = *(const bf8*)(&pool[H_OFF + (rt * 16 + lr) * 264 + ks * 32 + lg * 8]);
                #pragma unroll
                for (int c = 0; c < 4; ++c)
                    acc2[rt][c] = __builtin_amdgcn_mfma_f32_16x16x32_bf16(afr, bfr[c], acc2[rt][c], 0, 0, 0);
            }
        }
        #pragma unroll
        for (int c = 0; c < 4; ++c) {
            float bias = bl2[(wave * 4 + c) * 16 + lr];
            #pragma unroll
            for (int s = 0; s < 2; ++s) {
                f4 sv = (f4){0.f, 0.f, 0.f, 0.f};
                #pragma unroll
                for (int p = 0; p < 3; ++p)
                    #pragma unroll
                    for (int r = 0; r < 4; ++r)
                        sv[r] += fmaxf(acc2[p * 2 + s][c][r] + bias, 0.f);
                if (net == 0) {
                    s1p[s][c][0] = pk2(sv[0], sv[1]);
                    s1p[s][c][1] = pk2(sv[2], sv[3]);
                } else {
                    sacc[s][c] = sv;
                }
            }
        }
        __syncthreads();  // H reads done before next net overwrites H
    }

    // ---- Write S1 (h rows 0..31), S2 (rows 32..63) ----
    #pragma unroll
    for (int s = 0; s < 2; ++s)
        #pragma unroll
        for (int c = 0; c < 4; ++c) {
            int col = (wave * 4 + c) * 16 + lr;
            u32 a01 = pk2(sacc[s][c][0], sacc[s][c][1]);
            u32 a23 = pk2(sacc[s][c][2], sacc[s][c][3]);
            int base = H_OFF + (s * 16 + lg * 4) * 264 + col;
            pool[base]                  = (u16)s1p[s][c][0];
            pool[base + 264]            = (u16)(s1p[s][c][0] >> 16);
            pool[base + 2 * 264]        = (u16)s1p[s][c][1];
            pool[base + 3 * 264]        = (u16)(s1p[s][c][1] >> 16);
            pool[base + 8448]           = (u16)a01;
            pool[base + 8448 + 264]     = (u16)(a01 >> 16);
            pool[base + 8448 + 2 * 264] = (u16)a23;
            pool[base + 8448 + 3 * 264] = (u16)(a23 >> 16);
        }
    __syncthreads();

    // ---- Rho hidden layers, both nets in one MFMA phase ----
    {
        const u16* W5 = wsz + 163840;
        const u16* W7 = wsz + 229376;
        f4 racc[4][4];
        #pragma unroll
        for (int rt = 0; rt < 4; ++rt)
            #pragma unroll
            for (int c = 0; c < 4; ++c) racc[rt][c] = (f4){0.f, 0.f, 0.f, 0.f};
        #pragma unroll
        for (int ks = 0; ks < 8; ++ks) {
            bf8 bfr5[4], bfr7[4];
            #pragma unroll
            for (int c = 0; c < 4; ++c) {
                size_t off = (size_t)(((ks * 16 + wave * 4 + c) * 64 + lane) * 8);
                bfr5[c] = *(const bf8*)(W5 + off);
                bfr7[c] = *(const bf8*)(W7 + off);
            }
            #pragma unroll
            for (int rt = 0; rt < 2; ++rt) {
                bf8 a1 = *(const bf8*)(&pool[H_OFF + (rt * 16 + lr) * 264 + ks * 32 + lg * 8]);
                bf8 a2 = *(const bf8*)(&pool[H_OFF + 8448 + (rt * 16 + lr) * 264 + ks * 32 + lg * 8]);
                #pragma unroll
                for (int c = 0; c < 4; ++c) {
                    racc[rt][c]     = __builtin_amdgcn_mfma_f32_16x16x32_bf16(a1, bfr5[c], racc[rt][c], 0, 0, 0);
                    racc[2 + rt][c] = __builtin_amdgcn_mfma_f32_16x16x32_bf16(a2, bfr7[c], racc[2 + rt][c], 0, 0, 0);
                }
            }
        }
        // net0 epilogue -> RH0 (h rows 64..95, untouched by rho reads)
        #pragma unroll
        for (int c = 0; c < 4; ++c) {
            float bias = b5[(wave * 4 + c) * 16 + lr];
            #pragma unroll
            for (int rt = 0; rt < 2; ++rt) {
                u32 p01 = pk2(fmaxf(racc[rt][c][0] + bias, 0.f), fmaxf(racc[rt][c][1] + bias, 0.f));
                u32 p23 = pk2(fmaxf(racc[rt][c][2] + bias, 0.f), fmaxf(racc[rt][c][3] + bias, 0.f));
                int base = RH0 + (rt * 16 + lg * 4) * 264 + (wave * 4 + c) * 16 + lr;
                pool[base]           = (u16)p01;
                pool[base + 264]     = (u16)(p01 >> 16);
                pool[base + 2 * 264] = (u16)p23;
                pool[base + 3 * 264] = (u16)(p23 >> 16);
            }
        }
        __syncthreads();   // all S1 reads done before net1 overwrites it
        // net1 epilogue -> RH1 (over consumed S1)
        #pragma unroll
        for (int c = 0; c < 4; ++c) {
            float bias = b7[(wave * 4 + c) * 16 + lr];
            #pragma unroll
            for (int rt = 0; rt < 2; ++rt) {
                u32 p01 = pk2(fmaxf(racc[2 + rt][c][0] + bias, 0.f), fmaxf(racc[2 + rt][c][1] + bias, 0.f));
                u32 p23 = pk2(fmaxf(racc[2 + rt][c][2] + bias, 0.f), fmaxf(racc[2 + rt][c][3] + bias, 0.f));
                int base = RH1 + (rt * 16 + lg * 4) * 264 + (wave * 4 + c) * 16 + lr;
                pool[base]           = (u16)p01;
                pool[base + 264]     = (u16)(p01 >> 16);
                pool[base + 2 * 264] = (u16)p23;
                pool[base + 3 * 264] = (u16)(p23 >> 16);
            }
        }
        __syncthreads();
    }

    // ---- Final dots, split-K over 4 waves: q = rhoH @ w6 + b6. FP32 OUT. ----
    {
        int q = wave;                 // k-quarter
        int net = lane >> 5, r = lane & 31;
        int hoff = net ? RH1 : RH0;
        const float* wv = net ? w8 : w6;
        float s = 0.f;
        int base = hoff + r * 264 + q * 64;
        #pragma unroll
        for (int it = 0; it < 16; ++it) {
            uint2 two = *(const uint2*)&pool[base + it * 4];
            float4 wq = *(const float4*)(wv + q * 64 + it * 4);
            s += __uint_as_float(two.x << 16)          * wq.x;
            s += __uint_as_float(two.x & 0xffff0000u)  * wq.y;
            s += __uint_as_float(two.y << 16)          * wq.z;
            s += __uint_as_float(two.y & 0xffff0000u)  * wq.w;
        }
        __syncthreads();   // RH reads above done... (already synced; partials region is dead inp)
        ((u32*)pool)[t] = __float_as_uint(s);
    }
    __syncthreads();
    if (t < 64) {
        int net = t >> 5, r = t & 31;
        float qv = net ? b8[0] : b6[0];
        #pragma unroll
        for (int p = 0; p < 4; ++p)
            qv += __uint_as_float(((u32*)pool)[p * 64 + net * 32 + r]);
        out[net * B + wg * 32 + r] = qv;
    }
}

extern "C" void kernel_launch(void* const* d_in, const int* in_sizes, int n_in,
                              void* d_out, int out_size, void* d_ws, size_t ws_size,
                              hipStream_t stream) {
    const float* obs = (const float*)d_in[0];
    const float* ag  = (const float*)d_in[1];
    const float* g   = (const float*)d_in[2];
    const float* anc = (const float*)d_in[3];
    const float* act = (const float*)d_in[4];
    const float* w1  = (const float*)d_in[5];
    const float* b1  = (const float*)d_in[6];
    const float* w2  = (const float*)d_in[7];
    const float* b2  = (const float*)d_in[8];
    const float* w3  = (const float*)d_in[9];
    const float* b3  = (const float*)d_in[10];
    const float* w4  = (const float*)d_in[11];
    const float* b4  = (const float*)d_in[12];
    const float* w5  = (const float*)d_in[13];
    const float* b5  = (const float*)d_in[14];
    const float* w6  = (const float*)d_in[15];
    const float* b6  = (const float*)d_in[16];
    const float* w7  = (const float*)d_in[17];
    const float* b7  = (const float*)d_in[18];
    const float* w8  = (const float*)d_in[19];
    const float* b8  = (const float*)d_in[20];
    u16* ws    = (u16*)d_ws;
    float* out = (float*)d_out;
    int B = in_sizes[0] / 55;

    swz_all<<<36, 256, 0, stream>>>(w1, w3, w2, w4, w5, w7, ws);
    critic_kernel<<<(B + 31) / 32, 256, 0, stream>>>(obs, ag, g, anc, act,
                                                     b1, b2, b3, b4, b5, b7,
                                                     w6, b6, w8, b8, ws, out, B);
}